// Round 8
// baseline (97.206 us; speedup 1.0000x reference)
//
#include <hip/hip_runtime.h>
#include <hip/hip_bf16.h>
#include <math.h>

// vec[b,e] = sum_s softmax_s( tanh(theta@w.T [b,:] + h[b,s,:]@u) @ v ) * h[b,s,e]
// B=64, S=2048, E=256, T=100
// R8: async staging via global_load_lds width=16 (no VGPR round-trip, no
//     fp32->bf16 pack in stage). h tile kept fp32 in LDS; A-fragments built
//     at read time via cvt_pk. Swizzle = linear LDS dest + inverse-swizzled
//     per-lane global source + swizzled reads (rule #21). u streamed from L2
//     in a non-unrolled kt loop (no register ring -> no AGPR/VGPR blowup).

#define E_DIM 256
#define GM 32        // s-rows per block

typedef __bf16 bf16x8 __attribute__((ext_vector_type(8)));
typedef float  f32x4  __attribute__((ext_vector_type(4)));

__device__ __forceinline__ unsigned short f2bf(float x) {
    return __builtin_bit_cast(unsigned short, (__bf16)x);
}

// tanh(x) = 1 - 2/(exp(2x)+1); overflow-safe (rcp(inf)=0).
__device__ __forceinline__ float fast_tanh(float x) {
    const float e = __expf(2.0f * x);
    const float r = __builtin_amdgcn_rcpf(e + 1.0f);
    return fmaf(-2.0f, r, 1.0f);
}

// ---------------- Kernel 0: u_t[f][e] = bf16(u[e][f]) ----------------
__global__ __launch_bounds__(256) void k_transpose(const float* __restrict__ u,
                                                   unsigned short* __restrict__ u_t) {
    const int f = blockIdx.x, e = threadIdx.x;
    u_t[(size_t)f * E_DIM + e] = f2bf(u[(size_t)e * E_DIM + f]);
}

// ---------------- Kernel 1: tw[b,e] = sum_t theta[b,t] * w[e,t] ----------------
__global__ __launch_bounds__(E_DIM) void k_thetaw(const float* __restrict__ theta,
                                                  const float* __restrict__ w,
                                                  float* __restrict__ tw,
                                                  int T) {
    __shared__ float th[128];
    const int b = blockIdx.x;
    const int e = threadIdx.x;
    if (threadIdx.x < T) th[threadIdx.x] = theta[b * T + threadIdx.x];
    __syncthreads();
    float acc = 0.f;
    for (int t = 0; t < T; ++t) acc = fmaf(th[t], w[e * T + t], acc);
    tw[b * E_DIM + e] = acc;
}

// ---------------- Kernel 2 (fused): per (b, s-chunk of 32):
//   g_s = sum_f tanh(tw[b,f] + (h@u)[s,f]) * v[f]      (MFMA, bf16 inputs)
//   m = max_s g_s;  ex_s = exp(g_s - m);  d = sum ex_s
//   partial[e] = sum_s ex_s * h[s,e]                   (fp32 from resident LDS)
__global__ __launch_bounds__(256, 4) void k_gate_fused(const float* __restrict__ h,
                                                       const unsigned short* __restrict__ u_t,
                                                       const float* __restrict__ tw_,
                                                       const float* __restrict__ v,
                                                       float* __restrict__ partial,
                                                       float* __restrict__ pm,
                                                       float* __restrict__ pd,
                                                       int S, int SC) {
    __shared__ float h_lds[GM * E_DIM];   // 32 KB fp32; content pre-swizzled
    __shared__ float red[4][GM];          // 512 B
    __shared__ float exw[GM];             // 128 B
    __shared__ float pacc[4][E_DIM];      // 4 KB

    const int b   = blockIdx.y;
    const int sc  = blockIdx.x;
    const int tid = threadIdx.x;
    const int w   = tid >> 6;      // wave 0..3
    const int l   = tid & 63;      // lane
    const int lg  = l >> 4;        // k-group 0..3
    const int lc  = l & 15;        // row/col class 0..15
    const int f0w = w * 64;        // wave's f-range base

    // ---- async stage: 8 global_load_lds(16B) per wave; LDS dest linear,
    //      global source inverse-swizzled so reads can apply swz. ----
    // swz32(X) = X ^ ((X>>10)&7)<<4  (involution; fp32 rows are 1024 B)
    const char* hb = (const char*)(h + ((size_t)b * S + sc * GM) * E_DIM);
    char* ldsb = (char*)h_lds;
#pragma unroll
    for (int j = 0; j < 8; ++j) {
        const int row = j * 4 + w;                       // wave-uniform
        const unsigned srcoff = (unsigned)row * 1024u + (unsigned)((l ^ (row & 7)) * 16);
        __builtin_amdgcn_global_load_lds(
            (const __attribute__((address_space(1))) void*)(hb + srcoff),
            (__attribute__((address_space(3))) void*)(ldsb + row * 1024),
            16, 0, 0);
    }

    // ---- per-wave epilogue constants (overlap with staging) ----
    float tw_f[4], v_f[4];
#pragma unroll
    for (int n = 0; n < 4; ++n) {
        const int f = f0w + n * 16 + lc;
        tw_f[n] = tw_[b * E_DIM + f];
        v_f[n]  = v[f];
    }

    f32x4 acc[2][4];
#pragma unroll
    for (int m = 0; m < 2; ++m)
#pragma unroll
        for (int n = 0; n < 4; ++n)
            acc[m][n] = (f32x4){0.f, 0.f, 0.f, 0.f};

    const unsigned short* ubase = u_t + (size_t)(f0w + lc) * E_DIM + lg * 8;

    __syncthreads();   // drains vmcnt; h_lds ready

    // ---- K loop: 8 k-steps of 32. u fresh from L2 each step (TLP covers);
    //      NOT unrolled so the compiler can't hoist all u loads and spill. ----
#pragma unroll 1
    for (int kt = 0; kt < 8; ++kt) {
        // u fragments for this k-step (4 x 16B from L2)
        bf16x8 un[4];
#pragma unroll
        for (int n = 0; n < 4; ++n)
            un[n] = *reinterpret_cast<const bf16x8*>(ubase + n * 16 * E_DIM + kt * 32);

        // A fragments m=0,1: rows m*16+lc, cols kt*32+lg*8..+7 (fp32->bf16)
        bf16x8 af[2];
#pragma unroll
        for (int m = 0; m < 2; ++m) {
            const unsigned rb = (unsigned)(m * 16 + lc);
            const unsigned sw = (rb & 7) << 4;
            const unsigned cb = (unsigned)(kt * 128 + lg * 32);
            const f32x4 fa0 = *reinterpret_cast<const f32x4*>(ldsb + rb * 1024 + ((cb +  0) ^ sw));
            const f32x4 fa1 = *reinterpret_cast<const f32x4*>(ldsb + rb * 1024 + ((cb + 16) ^ sw));
#pragma unroll
            for (int jj = 0; jj < 4; ++jj) {
                af[m][jj]     = (__bf16)fa0[jj];
                af[m][4 + jj] = (__bf16)fa1[jj];
            }
        }

#pragma unroll
        for (int n = 0; n < 4; ++n) {
            acc[0][n] = __builtin_amdgcn_mfma_f32_16x16x32_bf16(af[0], un[n], acc[0][n], 0, 0, 0);
            acc[1][n] = __builtin_amdgcn_mfma_f32_16x16x32_bf16(af[1], un[n], acc[1][n], 0, 0, 0);
        }
    }

    // ---- gate epilogue: tanh(z+tw)*v, sum over f (lc-classes then waves) ----
    float part[2][4] = {};   // [m][i]; row = m*16 + lg*4 + i, col-class lc
#pragma unroll
    for (int n = 0; n < 4; ++n)
#pragma unroll
        for (int m = 0; m < 2; ++m)
#pragma unroll
            for (int i = 0; i < 4; ++i)
                part[m][i] += fast_tanh(acc[m][n][i] + tw_f[n]) * v_f[n];

#pragma unroll
    for (int off = 1; off < 16; off <<= 1)
#pragma unroll
        for (int m = 0; m < 2; ++m)
#pragma unroll
            for (int i = 0; i < 4; ++i)
                part[m][i] += __shfl_xor(part[m][i], off, 64);

    if (lc == 0) {
#pragma unroll
        for (int m = 0; m < 2; ++m)
#pragma unroll
            for (int i = 0; i < 4; ++i)
                red[w][m * 16 + lg * 4 + i] = part[m][i];
    }
    __syncthreads();

    // ---- block softmax stats: lanes 0..31 of wave 0 own the 32 g values ----
    if (tid < GM) {
        const float g = red[0][tid] + red[1][tid] + red[2][tid] + red[3][tid];
        float mx = g;
#pragma unroll
        for (int off = 1; off < 32; off <<= 1)
            mx = fmaxf(mx, __shfl_xor(mx, off, 64));
        const float ex = __expf(g - mx);
        float d = ex;
#pragma unroll
        for (int off = 1; off < 32; off <<= 1)
            d += __shfl_xor(d, off, 64);
        exw[tid] = ex;
        if (tid == 0) {
            pm[(size_t)b * SC + sc] = mx;
            pd[(size_t)b * SC + sc] = d;
        }
    }
    __syncthreads();

    // ---- weighted partial (fp32): wave w sums rows w*8..w*8+7 ----
    f32x4 a4 = (f32x4){0.f, 0.f, 0.f, 0.f};
#pragma unroll
    for (int j = 0; j < 8; ++j) {
        const int row = w * 8 + j;
        const float ws = exw[row];
        const f32x4 hv = *reinterpret_cast<const f32x4*>(
            ldsb + row * 1024 + ((l * 16) ^ ((row & 7) << 4)));
        a4[0] = fmaf(ws, hv[0], a4[0]);
        a4[1] = fmaf(ws, hv[1], a4[1]);
        a4[2] = fmaf(ws, hv[2], a4[2]);
        a4[3] = fmaf(ws, hv[3], a4[3]);
    }
    *reinterpret_cast<f32x4*>(&pacc[w][l * 4]) = a4;
    __syncthreads();

    const float p = pacc[0][tid] + pacc[1][tid] + pacc[2][tid] + pacc[3][tid];
    partial[((size_t)b * SC + sc) * E_DIM + tid] = p;
}

// ---------------- Kernel 3: exact softmax merge across chunks ----------------
__global__ __launch_bounds__(256) void k_combine(const float* __restrict__ partial,
                                                 const float* __restrict__ pm,
                                                 const float* __restrict__ pd,
                                                 float* __restrict__ out,
                                                 int SC) {
    const int b = blockIdx.x, t = threadIdx.x;
    __shared__ float sm[128], sd[128];
    if (t < SC) {
        sm[t] = pm[(size_t)b * SC + t];
        sd[t] = pd[(size_t)b * SC + t];
    }
    __syncthreads();

    float M = -3.4e38f;
    for (int c = 0; c < SC; ++c) M = fmaxf(M, sm[c]);

    float num = 0.f, den = 0.f;
    for (int c = 0; c < SC; ++c) {
        const float s = __expf(sm[c] - M);
        den = fmaf(s, sd[c], den);
        num = fmaf(s, partial[((size_t)b * SC + c) * E_DIM + t], num);
    }
    out[(size_t)b * E_DIM + t] = num / den;
}

extern "C" void kernel_launch(void* const* d_in, const int* in_sizes, int n_in,
                              void* d_out, int out_size, void* d_ws, size_t ws_size,
                              hipStream_t stream) {
    const float* h     = (const float*)d_in[0];
    const float* theta = (const float*)d_in[1];
    const float* w     = (const float*)d_in[2];
    const float* v     = (const float*)d_in[3];
    const float* u     = (const float*)d_in[4];
    float* out = (float*)d_out;

    const int E = in_sizes[3];              // 256
    const int T = in_sizes[2] / E;          // 100
    const int B = in_sizes[1] / T;          // 64
    const int S = in_sizes[0] / (B * E);    // 2048
    const int SC = S / GM;                  // 64

    float* tw = (float*)d_ws;                                     // [B,E]
    unsigned short* u_t = (unsigned short*)(tw + (size_t)B * E);  // [E,E] bf16
    float* partial = (float*)(u_t + (size_t)E * E);               // [B,SC,E]
    float* pm = partial + (size_t)B * SC * E;                     // [B,SC]
    float* pd = pm + (size_t)B * SC;                              // [B,SC]

    k_transpose<<<dim3(E), dim3(E), 0, stream>>>(u, u_t);
    k_thetaw<<<dim3(B), dim3(E), 0, stream>>>(theta, w, tw, T);
    k_gate_fused<<<dim3(SC, B), dim3(256), 0, stream>>>(h, u_t, tw, v, partial, pm, pd, S, SC);
    k_combine<<<dim3(B), dim3(256), 0, stream>>>(partial, pm, pd, out, SC);
}